// Round 7
// baseline (436.245 us; speedup 1.0000x reference)
//
#include <hip/hip_runtime.h>

#define NN 8192
#define FIN 128
#define FOUT 64
#define NSLICE 8
#define JSLICE (NN / NSLICE)   // 1024
#define JTILE 256
#define NT (JSLICE / JTILE)    // 4 tiles

typedef __attribute__((ext_vector_type(8))) short short8;
typedef __attribute__((ext_vector_type(4))) float floatx4;
typedef __attribute__((ext_vector_type(4))) unsigned short ushort4v;

__device__ __forceinline__ unsigned short f32_to_bf16(float f) {
    unsigned int u = __float_as_uint(f);
    return (unsigned short)((u + 0x7FFFu + ((u >> 16) & 1u)) >> 16);
}
__device__ __forceinline__ float bf16_to_f32(unsigned short b) {
    return __uint_as_float(((unsigned int)b) << 16);
}

// Kernel 1: wh = h @ W (fp32). Writes whB directly in MFMA B-fragment order
// (bf16), plus src[i] = wh[i].a1 + edge[i]*(wedge.a3), dst[i] = wh[i].a2.
// B-frag layout (numerically verified r3-r6): whB[(f*64+l)*8+i] = bf16(wh[row][feat]),
// f = T*8 + q*2 + c, row = T*64 + c*32 + (l>>4)*8 + i, feat = q*16 + (l&15).
__global__ __launch_bounds__(256) void gat_prep(
    const float* __restrict__ h,      // 8192x128
    const float* __restrict__ edge,   // 8192x1
    const float* __restrict__ weight, // 128x64
    const float* __restrict__ att,    // 192x1
    const float* __restrict__ wedge,  // 1x64
    unsigned short* __restrict__ whB, // bf16 fragment-order (1 MB)
    float* __restrict__ src,          // 8192
    float* __restrict__ dst)          // 8192
{
    __shared__ float wl[FIN * FOUT];   // 32 KB
    __shared__ float hl[16 * FIN];     // 8 KB
    const int tid = threadIdx.x;
    const int b = blockIdx.x;

    const float4* w4 = (const float4*)weight;
    float4* wl4 = (float4*)wl;
    for (int idx = tid; idx < FIN * FOUT / 4; idx += 256) wl4[idx] = w4[idx];
    const float4* h4 = (const float4*)(h + (size_t)b * 16 * FIN);
    float4* hl4 = (float4*)hl;
    for (int idx = tid; idx < 16 * FIN / 4; idx += 256) hl4[idx] = h4[idx];
    __syncthreads();

    const int wave = tid >> 6;
    const int lane = tid & 63;
    float acc[4] = {0.f, 0.f, 0.f, 0.f};
    for (int c = 0; c < FIN; ++c) {
        const float wv = wl[c * FOUT + lane];
#pragma unroll
        for (int r = 0; r < 4; ++r)
            acc[r] = fmaf(hl[(wave * 4 + r) * FIN + c], wv, acc[r]);
    }
    const int row0 = b * 16 + wave * 4;

    // whB fragment-order store
    {
        const int T = b >> 2;
        const int o = (b & 3) * 16 + wave * 4;
        const int c = o >> 5;
        const int quad = (o >> 3) & 3;
        const int i0 = o & 7;
        const int q = lane >> 4, col = lane & 15;
        const int f = T * 8 + q * 2 + c;
        const int elem = f * 64 + quad * 16 + col;
        ushort4v wb;
#pragma unroll
        for (int r = 0; r < 4; ++r) wb[r] = f32_to_bf16(acc[r]);
        *(ushort4v*)(whB + (size_t)elem * 8 + i0) = wb;
    }

    const float a1 = att[lane];
    const float a2 = att[FOUT + lane];
    float t3 = wedge[lane] * att[2 * FOUT + lane];
#pragma unroll
    for (int off = 32; off > 0; off >>= 1) t3 += __shfl_xor(t3, off, 64);

#pragma unroll
    for (int r = 0; r < 4; ++r) {
        float t1 = acc[r] * a1;
        float t2 = acc[r] * a2;
#pragma unroll
        for (int off = 32; off > 0; off >>= 1) {
            t1 += __shfl_xor(t1, off, 64);
            t2 += __shfl_xor(t2, off, 64);
        }
        if (lane == 0) {
            src[row0 + r] = t1 + edge[row0 + r] * t3;
            dst[row0 + r] = t2;
        }
    }
}

// Kernel 2: fused masked-softmax-numerator + P@Wh via MFMA — BARRIER-FREE.
// Each wave owns 16 rows end-to-end. Lane l computes P directly in MFMA
// A-fragment layout: row m = l&15, j = c*32 + (l>>4)*8 + i  -> pv IS the
// A-operand (no LDS round-trip, no inter-wave coupling, no __syncthreads in
// the loop). adj reads are coalesced: per k-chunk a wave touches 16 rows x
// 128 contiguous bytes. Compiler free to software-pipeline; 16 independent
// waves/CU hide HBM latency. Denominator: lane partial covers j = quad*8+i
// (mod 32); shfl_xor over quads (16,32) = exact row sum, consistent with the
// bf16-rounded numerator.
__global__ __launch_bounds__(256, 4) void gat_attn(
    const int* __restrict__ adj,
    const unsigned short* __restrict__ whB,
    const float* __restrict__ src,
    const float* __restrict__ dst,
    float* __restrict__ ws_acc,      // [NSLICE][8192][64]
    float* __restrict__ ws_l)        // [NSLICE][8192]
{
    __shared__ float dstL[JSLICE];   // 4 KB
    const int wave = threadIdx.x >> 6;
    const int lane = threadIdx.x & 63;
    const int m = lane & 15, quad = lane >> 4;
    const int iw0 = blockIdx.x * 64 + wave * 16;   // wave's 16 rows
    const int s = blockIdx.y;
    const size_t jbase = (size_t)s * JSLICE;

    {
        const float4* dg = (const float4*)(dst + jbase);
        float4* dl = (float4*)dstL;
        for (int idx = threadIdx.x; idx < JSLICE / 4; idx += 256) dl[idx] = dg[idx];
    }
    const float sm = src[iw0 + m];                         // per-lane row const
    const int* aprow = adj + (size_t)(iw0 + m) * NN + jbase;

    float lsum = 0.f;
    floatx4 acc[4] = {{0.f,0.f,0.f,0.f},{0.f,0.f,0.f,0.f},
                      {0.f,0.f,0.f,0.f},{0.f,0.f,0.f,0.f}};

    __syncthreads();   // dstL ready (only barrier in the kernel)

    for (int t = 0; t < NT; ++t) {
#pragma unroll
        for (int c = 0; c < 8; ++c) {
            const int off = t * JTILE + c * 32 + quad * 8;
            const int4 a0 = *(const int4*)(aprow + off);
            const int4 a1 = *(const int4*)(aprow + off + 4);
            const float4 d0 = *(const float4*)&dstL[off];
            const float4 d1 = *(const float4*)&dstL[off + 4];

            short8 pv;
            float v, p;
            v = sm + d0.x; v = fmaxf(v, 0.2f * v);
            p = (a0.x > 0) ? __expf(v) : 0.f; pv[0] = (short)f32_to_bf16(p);
            v = sm + d0.y; v = fmaxf(v, 0.2f * v);
            p = (a0.y > 0) ? __expf(v) : 0.f; pv[1] = (short)f32_to_bf16(p);
            v = sm + d0.z; v = fmaxf(v, 0.2f * v);
            p = (a0.z > 0) ? __expf(v) : 0.f; pv[2] = (short)f32_to_bf16(p);
            v = sm + d0.w; v = fmaxf(v, 0.2f * v);
            p = (a0.w > 0) ? __expf(v) : 0.f; pv[3] = (short)f32_to_bf16(p);
            v = sm + d1.x; v = fmaxf(v, 0.2f * v);
            p = (a1.x > 0) ? __expf(v) : 0.f; pv[4] = (short)f32_to_bf16(p);
            v = sm + d1.y; v = fmaxf(v, 0.2f * v);
            p = (a1.y > 0) ? __expf(v) : 0.f; pv[5] = (short)f32_to_bf16(p);
            v = sm + d1.z; v = fmaxf(v, 0.2f * v);
            p = (a1.z > 0) ? __expf(v) : 0.f; pv[6] = (short)f32_to_bf16(p);
            v = sm + d1.w; v = fmaxf(v, 0.2f * v);
            p = (a1.w > 0) ? __expf(v) : 0.f; pv[7] = (short)f32_to_bf16(p);

#pragma unroll
            for (int i = 0; i < 8; ++i)
                lsum += bf16_to_f32((unsigned short)pv[i]);

            // B-fragments for this 32-j chunk (L2-resident, 16 B/lane coalesced)
            const int j0g = (int)jbase + t * JTILE + c * 32;
            const int fb = (j0g >> 6) * 8 + ((j0g >> 5) & 1);
#pragma unroll
            for (int q = 0; q < 4; ++q) {
                const short8 bfr = *((const short8*)whB + (size_t)(fb + q * 2) * 64 + lane);
                acc[q] = __builtin_amdgcn_mfma_f32_16x16x32_bf16(pv, bfr, acc[q], 0, 0, 0);
            }
        }
    }

    // Row denominators: combine the 4 quad-lanes of each m
    lsum += __shfl_xor(lsum, 16, 64);
    lsum += __shfl_xor(lsum, 32, 64);
    if (lane < 16) ws_l[(size_t)s * NN + iw0 + lane] = lsum;

    // C/D layout: col = lane&15 (feature q*16+m), row = quad*4 + reg
#pragma unroll
    for (int q = 0; q < 4; ++q)
#pragma unroll
        for (int reg = 0; reg < 4; ++reg)
            ws_acc[(size_t)s * (NN * FOUT)
                   + (size_t)(iw0 + quad * 4 + reg) * FOUT + q * 16 + m] = acc[q][reg];
}

// Kernel 3: reduce NSLICE j-slices, divide by softmax denom, ELU.
__global__ __launch_bounds__(256) void gat_finish(
    const float* __restrict__ ws_acc, const float* __restrict__ ws_l,
    float* __restrict__ out)
{
    const int idx = blockIdx.x * 256 + threadIdx.x;   // 0 .. 8192*64-1
    const int i = idx >> 6;
    float a = 0.f, l = 0.f;
#pragma unroll
    for (int s = 0; s < NSLICE; ++s) {
        a += ws_acc[(size_t)s * (NN * FOUT) + idx];
        l += ws_l[(size_t)s * NN + i];
    }
    float v = a / l;
    out[idx] = (v > 0.f) ? v : expm1f(v);
}

extern "C" void kernel_launch(void* const* d_in, const int* in_sizes, int n_in,
                              void* d_out, int out_size, void* d_ws, size_t ws_size,
                              hipStream_t stream) {
    const float* h      = (const float*)d_in[0];
    const float* edge   = (const float*)d_in[1];
    const int*   adj    = (const int*)d_in[2];
    const float* weight = (const float*)d_in[3];
    const float* att    = (const float*)d_in[4];
    const float* wedge  = (const float*)d_in[5];
    float* out = (float*)d_out;

    unsigned short* whB = (unsigned short*)d_ws;          // 1 MB bf16 frags
    float* src    = (float*)(whB + (size_t)NN * FOUT);    // 8192
    float* dst    = src + NN;                             // 8192
    float* ws_l   = dst + NN;                             // NSLICE*8192
    float* ws_acc = ws_l + (size_t)NSLICE * NN;           // NSLICE*2 MB

    gat_prep<<<NN / 16, 256, 0, stream>>>(h, edge, weight, att, wedge, whB, src, dst);
    gat_attn<<<dim3(NN / 64, NSLICE), 256, 0, stream>>>(adj, whB, src, dst, ws_acc, ws_l);
    gat_finish<<<NN * FOUT / 256, 256, 0, stream>>>(ws_acc, ws_l, out);
}

// Round 8
// 425.681 us; speedup vs baseline: 1.0248x; 1.0248x over previous
//
#include <hip/hip_runtime.h>

#define NN 8192
#define FIN 128
#define FOUT 64
#define NSLICE 8
#define JSLICE (NN / NSLICE)   // 1024
#define NT64 (JSLICE / 64)     // 16 tiles of 64 j
#define PT_LD 72               // Pt row stride in shorts (pad 8; r5-verified 0 conflicts)

typedef __attribute__((ext_vector_type(8))) short short8;
typedef __attribute__((ext_vector_type(4))) float floatx4;
typedef __attribute__((ext_vector_type(4))) unsigned short ushort4v;

__device__ __forceinline__ unsigned short f32_to_bf16(float f) {
    unsigned int u = __float_as_uint(f);
    return (unsigned short)((u + 0x7FFFu + ((u >> 16) & 1u)) >> 16);
}
__device__ __forceinline__ float bf16_to_f32(unsigned short b) {
    return __uint_as_float(((unsigned int)b) << 16);
}

// Kernel 1: wh = h @ W (fp32). Writes whB directly in MFMA B-fragment order
// (bf16), plus src[i] = wh[i].a1 + edge[i]*(wedge.a3), dst[i] = wh[i].a2.
// B-frag layout (numerically verified r3-r7): whB[(f*64+l)*8+i] = bf16(wh[row][feat]),
// f = T*8 + q*2 + c, row = T*64 + c*32 + (l>>4)*8 + i, feat = q*16 + (l&15).
__global__ __launch_bounds__(256) void gat_prep(
    const float* __restrict__ h,      // 8192x128
    const float* __restrict__ edge,   // 8192x1
    const float* __restrict__ weight, // 128x64
    const float* __restrict__ att,    // 192x1
    const float* __restrict__ wedge,  // 1x64
    unsigned short* __restrict__ whB, // bf16 fragment-order (1 MB)
    float* __restrict__ src,          // 8192
    float* __restrict__ dst)          // 8192
{
    __shared__ float wl[FIN * FOUT];   // 32 KB
    __shared__ float hl[16 * FIN];     // 8 KB
    const int tid = threadIdx.x;
    const int b = blockIdx.x;

    const float4* w4 = (const float4*)weight;
    float4* wl4 = (float4*)wl;
    for (int idx = tid; idx < FIN * FOUT / 4; idx += 256) wl4[idx] = w4[idx];
    const float4* h4 = (const float4*)(h + (size_t)b * 16 * FIN);
    float4* hl4 = (float4*)hl;
    for (int idx = tid; idx < 16 * FIN / 4; idx += 256) hl4[idx] = h4[idx];
    __syncthreads();

    const int wave = tid >> 6;
    const int lane = tid & 63;
    float acc[4] = {0.f, 0.f, 0.f, 0.f};
    for (int c = 0; c < FIN; ++c) {
        const float wv = wl[c * FOUT + lane];
#pragma unroll
        for (int r = 0; r < 4; ++r)
            acc[r] = fmaf(hl[(wave * 4 + r) * FIN + c], wv, acc[r]);
    }
    const int row0 = b * 16 + wave * 4;

    // whB fragment-order store
    {
        const int T = b >> 2;
        const int o = (b & 3) * 16 + wave * 4;
        const int c = o >> 5;
        const int quad = (o >> 3) & 3;
        const int i0 = o & 7;
        const int q = lane >> 4, col = lane & 15;
        const int f = T * 8 + q * 2 + c;
        const int elem = f * 64 + quad * 16 + col;
        ushort4v wb;
#pragma unroll
        for (int r = 0; r < 4; ++r) wb[r] = f32_to_bf16(acc[r]);
        *(ushort4v*)(whB + (size_t)elem * 8 + i0) = wb;
    }

    const float a1 = att[lane];
    const float a2 = att[FOUT + lane];
    float t3 = wedge[lane] * att[2 * FOUT + lane];
#pragma unroll
    for (int off = 32; off > 0; off >>= 1) t3 += __shfl_xor(t3, off, 64);

#pragma unroll
    for (int r = 0; r < 4; ++r) {
        float t1 = acc[r] * a1;
        float t2 = acc[r] * a2;
#pragma unroll
        for (int off = 32; off > 0; off >>= 1) {
            t1 += __shfl_xor(t1, off, 64);
            t2 += __shfl_xor(t2, off, 64);
        }
        if (lane == 0) {
            src[row0 + r] = t1 + edge[row0 + r] * t3;
            dst[row0 + r] = t2;
        }
    }
}

// Kernel 2: fused masked-softmax-numerator + P@Wh via MFMA.
// Wave-independent (no s_barrier in loop) AND coalesced adj:
//  - Phase 1 lane map: row = g*4 + (lane>>4), j_local = (lane&15)*4 -> each
//    int4 instruction reads 4 adj rows x 256 B contiguous (coalesced).
//  - P transpose to A-fragment layout via WAVE-PRIVATE Pt in LDS: DS ops are
//    in program order within a wave -> no barrier, only lgkmcnt.
//  - VMEM order per tile: whB frags first, then adj(t+1) register prefetch,
//    then MFMA -> the MFMA's whB wait resolves at vmcnt(4), leaving the adj
//    prefetch in flight across compute. 16 independent waves/CU hide the rest.
__global__ __launch_bounds__(256, 4) void gat_attn(
    const int* __restrict__ adj,
    const unsigned short* __restrict__ whB,
    const float* __restrict__ src,
    const float* __restrict__ dst,
    float* __restrict__ ws_acc,      // [NSLICE][8192][64]
    float* __restrict__ ws_l)        // [NSLICE][8192]
{
    __shared__ float dstL[JSLICE];                 // 4 KB
    __shared__ unsigned short Pt[4][16][PT_LD];    // wave-private, ~9.2 KB total
    const int wave = threadIdx.x >> 6;
    const int lane = threadIdx.x & 63;
    const int m = lane & 15, quad = lane >> 4;
    const int jl = m * 4;                          // phase-1 j_local base
    const int iw0 = blockIdx.x * 64 + wave * 16;   // wave's 16 rows
    const int s = blockIdx.y;
    const size_t jbase = (size_t)s * JSLICE;

    {
        const float4* dg = (const float4*)(dst + jbase);
        float4* dl = (float4*)dstL;
        for (int idx = threadIdx.x; idx < JSLICE / 4; idx += 256) dl[idx] = dg[idx];
    }

    float srg[4];
    const int* aprow[4];
#pragma unroll
    for (int g = 0; g < 4; ++g) {
        srg[g] = src[iw0 + g * 4 + quad];
        aprow[g] = adj + (size_t)(iw0 + g * 4 + quad) * NN + jbase + jl;
    }
    float ls[4] = {0.f, 0.f, 0.f, 0.f};
    floatx4 acc[4] = {{0.f,0.f,0.f,0.f},{0.f,0.f,0.f,0.f},
                      {0.f,0.f,0.f,0.f},{0.f,0.f,0.f,0.f}};

    // Prefetch adj tile 0
    int4 av[2][4];
#pragma unroll
    for (int g = 0; g < 4; ++g) av[0][g] = *(const int4*)(aprow[g]);

    __syncthreads();   // dstL ready (only block barrier in the kernel)

#pragma unroll 2
    for (int t = 0; t < NT64; ++t) {
        const int b = t & 1;

        // whB B-fragments for this 64-j tile (L2-resident, 16 B/lane coalesced)
        const int Tg = (int)(jbase >> 6) + t;
        short8 bfr[8];
#pragma unroll
        for (int f = 0; f < 8; ++f)
            bfr[f] = *((const short8*)whB + ((size_t)(Tg * 8 + f)) * 64 + lane);

        // adj prefetch for t+1 (issued after whB -> stays in flight through MFMA)
        if (t + 1 < NT64) {
#pragma unroll
            for (int g = 0; g < 4; ++g)
                av[b ^ 1][g] = *(const int4*)(aprow[g] + (t + 1) * 64);
        }

        // Phase 1: exp-compute from av[b]; write wave-private Pt
        const float4 dv = *(const float4*)&dstL[t * 64 + jl];
#pragma unroll
        for (int g = 0; g < 4; ++g) {
            ushort4v pv;
            float v, p;
            v = srg[g] + dv.x; v = fmaxf(v, 0.2f * v);
            p = (av[b][g].x > 0) ? __expf(v) : 0.f; pv.x = f32_to_bf16(p);
            v = srg[g] + dv.y; v = fmaxf(v, 0.2f * v);
            p = (av[b][g].y > 0) ? __expf(v) : 0.f; pv.y = f32_to_bf16(p);
            v = srg[g] + dv.z; v = fmaxf(v, 0.2f * v);
            p = (av[b][g].z > 0) ? __expf(v) : 0.f; pv.z = f32_to_bf16(p);
            v = srg[g] + dv.w; v = fmaxf(v, 0.2f * v);
            p = (av[b][g].w > 0) ? __expf(v) : 0.f; pv.w = f32_to_bf16(p);
            ls[g] += bf16_to_f32(pv.x) + bf16_to_f32(pv.y)
                   + bf16_to_f32(pv.z) + bf16_to_f32(pv.w);
            *(ushort4v*)&Pt[wave][g * 4 + quad][jl] = pv;
        }

        // Wave-local LDS round-trip: in-order DS + lgkm wait, NO barrier
        __builtin_amdgcn_s_waitcnt(0xC07F);   // lgkmcnt(0)

        const short8 a0 = *(const short8*)&Pt[wave][m][quad * 8];
        const short8 a1 = *(const short8*)&Pt[wave][m][32 + quad * 8];
#pragma unroll
        for (int q = 0; q < 4; ++q) {
            acc[q] = __builtin_amdgcn_mfma_f32_16x16x32_bf16(a0, bfr[q * 2 + 0], acc[q], 0, 0, 0);
            acc[q] = __builtin_amdgcn_mfma_f32_16x16x32_bf16(a1, bfr[q * 2 + 1], acc[q], 0, 0, 0);
        }
    }

    // Row denominators: ls[g] covers row g*4+quad, j = jl..jl+3 (all tiles);
    // reduce across the 16 lanes sharing quad (xor 1,2,4,8).
#pragma unroll
    for (int g = 0; g < 4; ++g) {
#pragma unroll
        for (int off = 1; off < 16; off <<= 1)
            ls[g] += __shfl_xor(ls[g], off, 64);
    }
    if (m == 0) {
#pragma unroll
        for (int g = 0; g < 4; ++g)
            ws_l[(size_t)s * NN + iw0 + g * 4 + quad] = ls[g];
    }

    // C/D layout: col = lane&15 (feature q*16+m), row = quad*4 + reg
#pragma unroll
    for (int q = 0; q < 4; ++q)
#pragma unroll
        for (int reg = 0; reg < 4; ++reg)
            ws_acc[(size_t)s * (NN * FOUT)
                   + (size_t)(iw0 + quad * 4 + reg) * FOUT + q * 16 + m] = acc[q][reg];
}

// Kernel 3: reduce NSLICE j-slices, divide by softmax denom, ELU.
__global__ __launch_bounds__(256) void gat_finish(
    const float* __restrict__ ws_acc, const float* __restrict__ ws_l,
    float* __restrict__ out)
{
    const int idx = blockIdx.x * 256 + threadIdx.x;   // 0 .. 8192*64-1
    const int i = idx >> 6;
    float a = 0.f, l = 0.f;
#pragma unroll
    for (int s = 0; s < NSLICE; ++s) {
        a += ws_acc[(size_t)s * (NN * FOUT) + idx];
        l += ws_l[(size_t)s * NN + i];
    }
    float v = a / l;
    out[idx] = (v > 0.f) ? v : expm1f(v);
}

extern "C" void kernel_launch(void* const* d_in, const int* in_sizes, int n_in,
                              void* d_out, int out_size, void* d_ws, size_t ws_size,
                              hipStream_t stream) {
    const float* h      = (const float*)d_in[0];
    const float* edge   = (const float*)d_in[1];
    const int*   adj    = (const int*)d_in[2];
    const float* weight = (const float*)d_in[3];
    const float* att    = (const float*)d_in[4];
    const float* wedge  = (const float*)d_in[5];
    float* out = (float*)d_out;

    unsigned short* whB = (unsigned short*)d_ws;          // 1 MB bf16 frags
    float* src    = (float*)(whB + (size_t)NN * FOUT);    // 8192
    float* dst    = src + NN;                             // 8192
    float* ws_l   = dst + NN;                             // NSLICE*8192
    float* ws_acc = ws_l + (size_t)NSLICE * NN;           // NSLICE*2 MB

    gat_prep<<<NN / 16, 256, 0, stream>>>(h, edge, weight, att, wedge, whB, src, dst);
    gat_attn<<<dim3(NN / 64, NSLICE), 256, 0, stream>>>(adj, whB, src, dst, ws_acc, ws_l);
    gat_finish<<<NN * FOUT / 256, 256, 0, stream>>>(ws_acc, ws_l, out);
}

// Round 9
// 424.299 us; speedup vs baseline: 1.0282x; 1.0033x over previous
//
#include <hip/hip_runtime.h>

#define NN 8192
#define FIN 128
#define FOUT 64
#define NSLICE 4
#define JSLICE (NN / NSLICE)   // 2048
#define JTILE 256
#define NT (JSLICE / JTILE)    // 8
#define PT_LD 264              // Pt row stride in shorts: 256 + 8 pad
#define NCHUNK (NN * NN / 256) // 262144 chunks of 256 adj elements

typedef __attribute__((ext_vector_type(8))) short short8;
typedef __attribute__((ext_vector_type(4))) float floatx4;
typedef __attribute__((ext_vector_type(4))) unsigned short ushort4v;

__device__ __forceinline__ unsigned short f32_to_bf16(float f) {
    unsigned int u = __float_as_uint(f);
    return (unsigned short)((u + 0x7FFFu + ((u >> 16) & 1u)) >> 16);
}
__device__ __forceinline__ float bf16_to_f32(unsigned short b) {
    return __uint_as_float(((unsigned int)b) << 16);
}

// Kernel 0: adj (268 MB int32) -> ballot bitmask (8.4 MB). Pure streaming,
// fill-kernel shape: 2048 blocks, int4/lane (1 KB/wave-instr), 4-deep unroll.
// Chunk c covers adj flat [c*256, c*256+256); word k (k=0..3) bit l =
// (adj[c*256 + l*4 + k] > 0)  -- exactly the element attn's phase-1 lane l,
// subcomponent k consumes.
__global__ __launch_bounds__(256) void gat_pack(
    const int* __restrict__ adj, unsigned long long* __restrict__ amask)
{
    const int gw = (blockIdx.x * 256 + threadIdx.x) >> 6;  // global wave 0..8191
    const int lane = threadIdx.x & 63;
    const int4* adj4 = (const int4*)adj;
    const int c0 = gw * (NCHUNK / 8192);                   // 32 chunks per wave
#pragma unroll 4
    for (int it = 0; it < NCHUNK / 8192; ++it) {
        const int c = c0 + it;
        const int4 a = adj4[(size_t)c * 64 + lane];
        const unsigned long long b0 = __ballot(a.x > 0);
        const unsigned long long b1 = __ballot(a.y > 0);
        const unsigned long long b2 = __ballot(a.z > 0);
        const unsigned long long b3 = __ballot(a.w > 0);
        if (lane == 0) {
            ulonglong2* mw = (ulonglong2*)(amask + (size_t)c * 4);
            mw[0] = make_ulonglong2(b0, b1);
            mw[1] = make_ulonglong2(b2, b3);
        }
    }
}

// Kernel 1: wh = h @ W (fp32). Writes whB directly in MFMA B-fragment order
// (bf16), plus src[i] = wh[i].a1 + edge[i]*(wedge.a3), dst[i] = wh[i].a2.
// B-frag layout (numerically verified r3-r8): whB[(f*64+l)*8+i] = bf16(wh[row][feat]),
// f = T*8 + q*2 + c, row = T*64 + c*32 + (l>>4)*8 + i, feat = q*16 + (l&15).
__global__ __launch_bounds__(256) void gat_prep(
    const float* __restrict__ h,      // 8192x128
    const float* __restrict__ edge,   // 8192x1
    const float* __restrict__ weight, // 128x64
    const float* __restrict__ att,    // 192x1
    const float* __restrict__ wedge,  // 1x64
    unsigned short* __restrict__ whB, // bf16 fragment-order (1 MB)
    float* __restrict__ src,          // 8192
    float* __restrict__ dst)          // 8192
{
    __shared__ float wl[FIN * FOUT];   // 32 KB
    __shared__ float hl[16 * FIN];     // 8 KB
    const int tid = threadIdx.x;
    const int b = blockIdx.x;

    const float4* w4 = (const float4*)weight;
    float4* wl4 = (float4*)wl;
    for (int idx = tid; idx < FIN * FOUT / 4; idx += 256) wl4[idx] = w4[idx];
    const float4* h4 = (const float4*)(h + (size_t)b * 16 * FIN);
    float4* hl4 = (float4*)hl;
    for (int idx = tid; idx < 16 * FIN / 4; idx += 256) hl4[idx] = h4[idx];
    __syncthreads();

    const int wave = tid >> 6;
    const int lane = tid & 63;
    float acc[4] = {0.f, 0.f, 0.f, 0.f};
    for (int c = 0; c < FIN; ++c) {
        const float wv = wl[c * FOUT + lane];
#pragma unroll
        for (int r = 0; r < 4; ++r)
            acc[r] = fmaf(hl[(wave * 4 + r) * FIN + c], wv, acc[r]);
    }
    const int row0 = b * 16 + wave * 4;

    // whB fragment-order store
    {
        const int T = b >> 2;
        const int o = (b & 3) * 16 + wave * 4;
        const int c = o >> 5;
        const int quad = (o >> 3) & 3;
        const int i0 = o & 7;
        const int q = lane >> 4, col = lane & 15;
        const int f = T * 8 + q * 2 + c;
        const int elem = f * 64 + quad * 16 + col;
        ushort4v wb;
#pragma unroll
        for (int r = 0; r < 4; ++r) wb[r] = f32_to_bf16(acc[r]);
        *(ushort4v*)(whB + (size_t)elem * 8 + i0) = wb;
    }

    const float a1 = att[lane];
    const float a2 = att[FOUT + lane];
    float t3 = wedge[lane] * att[2 * FOUT + lane];
#pragma unroll
    for (int off = 32; off > 0; off >>= 1) t3 += __shfl_xor(t3, off, 64);

#pragma unroll
    for (int r = 0; r < 4; ++r) {
        float t1 = acc[r] * a1;
        float t2 = acc[r] * a2;
#pragma unroll
        for (int off = 32; off > 0; off >>= 1) {
            t1 += __shfl_xor(t1, off, 64);
            t2 += __shfl_xor(t2, off, 64);
        }
        if (lane == 0) {
            src[row0 + r] = t1 + edge[row0 + r] * t3;
            dst[row0 + r] = t2;
        }
    }
}

// Kernel 2: fused masked-softmax-numerator + P@Wh via MFMA (r5 structure, r9
// inputs): adj replaced by L2-resident bitmask -> VMEM is tiny, the 2-barrier
// loop runs at its compute floor. Phase 1: lane l owns j = t*256 + 4l..4l+3;
// mask word k bit l gates subcomponent k. Phase 2: 8 MFMAs over K=256
// (A-frags via LDS Pt, B pre-swizzled whB). No max-subtraction needed:
// v = lrelu(src+dst) bounded; denominator uses bf16-rounded p = consistent
// with the MFMA numerator.
__global__ __launch_bounds__(256) void gat_attn(
    const unsigned long long* __restrict__ amask,  // [NN][32] chunks x 4 words
    const unsigned short* __restrict__ whB,
    const float* __restrict__ src,
    const float* __restrict__ dst,
    float* __restrict__ ws_acc,      // [NSLICE][8192][64]
    float* __restrict__ ws_l)        // [NSLICE][8192]
{
    __shared__ unsigned short Pt[16][PT_LD];   // 8.4 KB
    __shared__ float dstL[JSLICE];             // 8 KB
    const int wave = threadIdx.x >> 6;
    const int lane = threadIdx.x & 63;
    const int i0 = blockIdx.x * 16;
    const int s  = blockIdx.y;
    const size_t jbase = (size_t)s * JSLICE;
    const int m = lane & 15, quad = lane >> 4;

    {
        const float4* dg = (const float4*)(dst + jbase);
        float4* dl = (float4*)dstL;
        for (int idx = threadIdx.x; idx < JSLICE / 4; idx += 256) dl[idx] = dg[idx];
    }

    float sr[4];
    const unsigned long long* mp[4];
#pragma unroll
    for (int r = 0; r < 4; ++r) {
        const int row = i0 + wave * 4 + r;
        sr[r] = src[row];
        mp[r] = amask + ((size_t)row * (NN / 256) + s * NT) * 4;
    }
    float lsum[4] = {0.f, 0.f, 0.f, 0.f};
    floatx4 acc = {0.f, 0.f, 0.f, 0.f};

    __syncthreads();   // dstL ready

    for (int t = 0; t < NT; ++t) {
        // ---- Phase 1: lane l handles j = t*256 + 4l..4l+3
        const float4 dv = *(const float4*)&dstL[t * JTILE + 4 * lane];
#pragma unroll
        for (int r = 0; r < 4; ++r) {
            const ulonglong2 ma = *(const ulonglong2*)(mp[r] + t * 4);
            const ulonglong2 mb = *(const ulonglong2*)(mp[r] + t * 4 + 2);
            ushort4v pv;
            float v, p;
            v = sr[r] + dv.x; v = fmaxf(v, 0.2f * v);
            p = ((ma.x >> lane) & 1ull) ? __expf(v) : 0.f; pv.x = f32_to_bf16(p);
            v = sr[r] + dv.y; v = fmaxf(v, 0.2f * v);
            p = ((ma.y >> lane) & 1ull) ? __expf(v) : 0.f; pv.y = f32_to_bf16(p);
            v = sr[r] + dv.z; v = fmaxf(v, 0.2f * v);
            p = ((mb.x >> lane) & 1ull) ? __expf(v) : 0.f; pv.z = f32_to_bf16(p);
            v = sr[r] + dv.w; v = fmaxf(v, 0.2f * v);
            p = ((mb.y >> lane) & 1ull) ? __expf(v) : 0.f; pv.w = f32_to_bf16(p);
            lsum[r] += bf16_to_f32(pv.x) + bf16_to_f32(pv.y)
                     + bf16_to_f32(pv.z) + bf16_to_f32(pv.w);
            *(ushort4v*)&Pt[wave * 4 + r][4 * lane] = pv;
        }
        __syncthreads();

        // ---- Phase 2: 8 MFMAs over K=256 (indexing verified r4/r5)
        const int jt0 = (int)((jbase + (size_t)t * JTILE) >> 6);
#pragma unroll
        for (int kk = 0; kk < 8; ++kk) {
            const short8 a = *(const short8*)&Pt[m][kk * 32 + quad * 8];
            const int f = (jt0 + (kk >> 1)) * 8 + wave * 2 + (kk & 1);
            const short8 bfr = *((const short8*)whB + (size_t)f * 64 + lane);
            acc = __builtin_amdgcn_mfma_f32_16x16x32_bf16(a, bfr, acc, 0, 0, 0);
        }
        __syncthreads();
    }

#pragma unroll
    for (int r = 0; r < 4; ++r) {
#pragma unroll
        for (int off = 32; off > 0; off >>= 1)
            lsum[r] += __shfl_xor(lsum[r], off, 64);
    }
    if (lane == 0) {
#pragma unroll
        for (int r = 0; r < 4; ++r)
            ws_l[(size_t)s * NN + i0 + wave * 4 + r] = lsum[r];
    }

    // C/D layout: col = lane&15, row = quad*4 + reg
#pragma unroll
    for (int reg = 0; reg < 4; ++reg) {
        const int row = quad * 4 + reg;
        ws_acc[(size_t)s * (NN * FOUT) + (size_t)(i0 + row) * FOUT + wave * 16 + m] = acc[reg];
    }
}

// Kernel 3: reduce NSLICE j-slices, divide by softmax denom, ELU.
__global__ __launch_bounds__(256) void gat_finish(
    const float* __restrict__ ws_acc, const float* __restrict__ ws_l,
    float* __restrict__ out)
{
    const int idx = blockIdx.x * 256 + threadIdx.x;   // 0 .. 8192*64-1
    const int i = idx >> 6;
    float a = 0.f, l = 0.f;
#pragma unroll
    for (int s = 0; s < NSLICE; ++s) {
        a += ws_acc[(size_t)s * (NN * FOUT) + idx];
        l += ws_l[(size_t)s * NN + i];
    }
    float v = a / l;
    out[idx] = (v > 0.f) ? v : expm1f(v);
}

extern "C" void kernel_launch(void* const* d_in, const int* in_sizes, int n_in,
                              void* d_out, int out_size, void* d_ws, size_t ws_size,
                              hipStream_t stream) {
    const float* h      = (const float*)d_in[0];
    const float* edge   = (const float*)d_in[1];
    const int*   adj    = (const int*)d_in[2];
    const float* weight = (const float*)d_in[3];
    const float* att    = (const float*)d_in[4];
    const float* wedge  = (const float*)d_in[5];
    float* out = (float*)d_out;

    unsigned short* whB = (unsigned short*)d_ws;          // 1 MB bf16 frags
    float* src    = (float*)(whB + (size_t)NN * FOUT);    // 8192
    float* dst    = src + NN;                             // 8192
    float* ws_l   = dst + NN;                             // NSLICE*8192
    float* ws_acc = ws_l + (size_t)NSLICE * NN;           // 8 MB
    unsigned long long* amask =
        (unsigned long long*)(ws_acc + (size_t)NSLICE * NN * FOUT);  // 8.4 MB

    gat_pack<<<2048, 256, 0, stream>>>(adj, amask);
    gat_prep<<<NN / 16, 256, 0, stream>>>(h, edge, weight, att, wedge, whB, src, dst);
    gat_attn<<<dim3(NN / 16, NSLICE), 256, 0, stream>>>(amask, whB, src, dst, ws_acc, ws_l);
    gat_finish<<<NN * FOUT / 256, 256, 0, stream>>>(ws_acc, ws_l, out);
}

// Round 10
// 397.966 us; speedup vs baseline: 1.0962x; 1.0662x over previous
//
#include <hip/hip_runtime.h>

#define NN 8192
#define FIN 128
#define FOUT 64
#define NSLICE 4
#define JSLICE (NN / NSLICE)   // 2048
#define NT 8                   // 8 phase-1 tiles of 256 j
#define PT_LD 2056             // row stride in shorts = 1028 dwords ≡ 4 (mod 32): ≤2-way conflicts

typedef __attribute__((ext_vector_type(8))) short short8;
typedef __attribute__((ext_vector_type(4))) float floatx4;
typedef __attribute__((ext_vector_type(4))) unsigned short ushort4v;

__device__ __forceinline__ unsigned short f32_to_bf16(float f) {
    unsigned int u = __float_as_uint(f);
    return (unsigned short)((u + 0x7FFFu + ((u >> 16) & 1u)) >> 16);
}
__device__ __forceinline__ float bf16_to_f32(unsigned short b) {
    return __uint_as_float(((unsigned int)b) << 16);
}

// Kernel 1: wh = h @ W (fp32). Writes whB directly in MFMA B-fragment order
// (bf16), plus src[i] = wh[i].a1 + edge[i]*(wedge.a3), dst[i] = wh[i].a2.
// B-frag layout (numerically verified r3-r9): whB[(f*64+l)*8+i] = bf16(wh[row][feat]),
// f = T*8 + q*2 + c, row = T*64 + c*32 + (l>>4)*8 + i, feat = q*16 + (l&15).
__global__ __launch_bounds__(256) void gat_prep(
    const float* __restrict__ h,      // 8192x128
    const float* __restrict__ edge,   // 8192x1
    const float* __restrict__ weight, // 128x64
    const float* __restrict__ att,    // 192x1
    const float* __restrict__ wedge,  // 1x64
    unsigned short* __restrict__ whB, // bf16 fragment-order (1 MB)
    float* __restrict__ src,          // 8192
    float* __restrict__ dst)          // 8192
{
    __shared__ float wl[FIN * FOUT];   // 32 KB
    __shared__ float hl[16 * FIN];     // 8 KB
    const int tid = threadIdx.x;
    const int b = blockIdx.x;

    const float4* w4 = (const float4*)weight;
    float4* wl4 = (float4*)wl;
    for (int idx = tid; idx < FIN * FOUT / 4; idx += 256) wl4[idx] = w4[idx];
    const float4* h4 = (const float4*)(h + (size_t)b * 16 * FIN);
    float4* hl4 = (float4*)hl;
    for (int idx = tid; idx < 16 * FIN / 4; idx += 256) hl4[idx] = h4[idx];
    __syncthreads();

    const int wave = tid >> 6;
    const int lane = tid & 63;
    float acc[4] = {0.f, 0.f, 0.f, 0.f};
    for (int c = 0; c < FIN; ++c) {
        const float wv = wl[c * FOUT + lane];
#pragma unroll
        for (int r = 0; r < 4; ++r)
            acc[r] = fmaf(hl[(wave * 4 + r) * FIN + c], wv, acc[r]);
    }
    const int row0 = b * 16 + wave * 4;

    // whB fragment-order store
    {
        const int T = b >> 2;
        const int o = (b & 3) * 16 + wave * 4;
        const int c = o >> 5;
        const int quad = (o >> 3) & 3;
        const int i0 = o & 7;
        const int q = lane >> 4, col = lane & 15;
        const int f = T * 8 + q * 2 + c;
        const int elem = f * 64 + quad * 16 + col;
        ushort4v wb;
#pragma unroll
        for (int r = 0; r < 4; ++r) wb[r] = f32_to_bf16(acc[r]);
        *(ushort4v*)(whB + (size_t)elem * 8 + i0) = wb;
    }

    const float a1 = att[lane];
    const float a2 = att[FOUT + lane];
    float t3 = wedge[lane] * att[2 * FOUT + lane];
#pragma unroll
    for (int off = 32; off > 0; off >>= 1) t3 += __shfl_xor(t3, off, 64);

#pragma unroll
    for (int r = 0; r < 4; ++r) {
        float t1 = acc[r] * a1;
        float t2 = acc[r] * a2;
#pragma unroll
        for (int off = 32; off > 0; off >>= 1) {
            t1 += __shfl_xor(t1, off, 64);
            t2 += __shfl_xor(t2, off, 64);
        }
        if (lane == 0) {
            src[row0 + r] = t1 + edge[row0 + r] * t3;
            dst[row0 + r] = t2;
        }
    }
}

// Kernel 2: fused masked-softmax-numerator + P@Wh via MFMA — ONE barrier.
// Phase 1 (barrier-free): full 2048-j slice of P computed into Pt[16][2048]
// (66 KB LDS, 2 blocks/CU) with distance-2 register prefetch of adj/dst —
// waves run free, ~40 KB/CU of adj in flight -> phase 1 streams at HBM rate.
// One __syncthreads. Phase 2 (barrier-free): 64 MFMAs, 64 independent
// ds_read_b128 + 64 L2-resident whB loads, 2 acc chains for MFMA ILP.
// r9's verified indexing throughout. No max-subtraction (v bounded);
// denominator uses bf16-rounded p = consistent with MFMA numerator.
__global__ __launch_bounds__(256) void gat_attn(
    const int* __restrict__ adj,
    const unsigned short* __restrict__ whB,
    const float* __restrict__ src,
    const float* __restrict__ dst,
    float* __restrict__ ws_acc,      // [NSLICE][8192][64]
    float* __restrict__ ws_l)        // [NSLICE][8192]
{
    __shared__ unsigned short Pt[16][PT_LD];   // 65.8 KB
    const int wave = threadIdx.x >> 6;
    const int lane = threadIdx.x & 63;
    const int i0 = blockIdx.x * 16;
    const int s  = blockIdx.y;
    const size_t jbase = (size_t)s * JSLICE;
    const int m = lane & 15, quad = lane >> 4;

    float sr[4];
    const int4* ap[4];
#pragma unroll
    for (int r = 0; r < 4; ++r) {
        const int row = i0 + wave * 4 + r;
        sr[r] = src[row];
        ap[r] = (const int4*)(adj + (size_t)row * NN + jbase);
    }
    const float4* dst4 = (const float4*)(dst + jbase);
    float lsum[4] = {0.f, 0.f, 0.f, 0.f};

    // ---- Phase 1: distance-2 prefetch, no barriers. Lane l owns j = t*256+4l..4l+3.
    int4 av[2][4];
    float4 dv[2];
#pragma unroll
    for (int r = 0; r < 4; ++r) av[0][r] = ap[r][lane];
    dv[0] = dst4[lane];
#pragma unroll
    for (int r = 0; r < 4; ++r) av[1][r] = ap[r][64 + lane];
    dv[1] = dst4[64 + lane];

    for (int t = 0; t < NT; ++t) {
        const int b = t & 1;
        int4 a4[4];
#pragma unroll
        for (int r = 0; r < 4; ++r) a4[r] = av[b][r];
        const float4 dvl = dv[b];

        if (t + 2 < NT) {
#pragma unroll
            for (int r = 0; r < 4; ++r) av[b][r] = ap[r][(t + 2) * 64 + lane];
            dv[b] = dst4[(t + 2) * 64 + lane];
        }

#pragma unroll
        for (int r = 0; r < 4; ++r) {
            ushort4v pv;
            float v, p;
            v = sr[r] + dvl.x; v = fmaxf(v, 0.2f * v);
            p = (a4[r].x > 0) ? __expf(v) : 0.f; pv.x = f32_to_bf16(p);
            v = sr[r] + dvl.y; v = fmaxf(v, 0.2f * v);
            p = (a4[r].y > 0) ? __expf(v) : 0.f; pv.y = f32_to_bf16(p);
            v = sr[r] + dvl.z; v = fmaxf(v, 0.2f * v);
            p = (a4[r].z > 0) ? __expf(v) : 0.f; pv.z = f32_to_bf16(p);
            v = sr[r] + dvl.w; v = fmaxf(v, 0.2f * v);
            p = (a4[r].w > 0) ? __expf(v) : 0.f; pv.w = f32_to_bf16(p);
            lsum[r] += bf16_to_f32(pv.x) + bf16_to_f32(pv.y)
                     + bf16_to_f32(pv.z) + bf16_to_f32(pv.w);
            *(ushort4v*)&Pt[wave * 4 + r][t * 256 + 4 * lane] = pv;
        }
    }

    __syncthreads();   // the ONLY barrier

    // ---- Phase 2: 64 MFMAs over K=2048, 2 acc chains.
    // f = ((jbase>>6) + (kk>>1))*8 + wave*2 + (kk&1)  (r9-verified)
    const size_t jt8 = ((size_t)(jbase >> 6)) * 8 + wave * 2;
    floatx4 acc0 = {0.f, 0.f, 0.f, 0.f};
    floatx4 acc1 = {0.f, 0.f, 0.f, 0.f};
#pragma unroll 8
    for (int kk = 0; kk < 64; kk += 2) {
        const short8 a0 = *(const short8*)&Pt[m][kk * 32 + quad * 8];
        const short8 a1 = *(const short8*)&Pt[m][kk * 32 + 32 + quad * 8];
        const short8 b0 = *((const short8*)whB + (jt8 + (size_t)(kk >> 1) * 8) * 64 + lane);
        const short8 b1 = *((const short8*)whB + (jt8 + (size_t)(kk >> 1) * 8 + 1) * 64 + lane);
        acc0 = __builtin_amdgcn_mfma_f32_16x16x32_bf16(a0, b0, acc0, 0, 0, 0);
        acc1 = __builtin_amdgcn_mfma_f32_16x16x32_bf16(a1, b1, acc1, 0, 0, 0);
    }

#pragma unroll
    for (int r = 0; r < 4; ++r) {
#pragma unroll
        for (int off = 32; off > 0; off >>= 1)
            lsum[r] += __shfl_xor(lsum[r], off, 64);
    }
    if (lane == 0) {
#pragma unroll
        for (int r = 0; r < 4; ++r)
            ws_l[(size_t)s * NN + i0 + wave * 4 + r] = lsum[r];
    }

    // C/D layout: col = lane&15 (feature wave*16+m), row = quad*4 + reg
#pragma unroll
    for (int reg = 0; reg < 4; ++reg) {
        const int row = quad * 4 + reg;
        ws_acc[(size_t)s * (NN * FOUT) + (size_t)(i0 + row) * FOUT + wave * 16 + m]
            = acc0[reg] + acc1[reg];
    }
}

// Kernel 3: reduce NSLICE j-slices, divide by softmax denom, ELU.
__global__ __launch_bounds__(256) void gat_finish(
    const float* __restrict__ ws_acc, const float* __restrict__ ws_l,
    float* __restrict__ out)
{
    const int idx = blockIdx.x * 256 + threadIdx.x;   // 0 .. 8192*64-1
    const int i = idx >> 6;
    float a = 0.f, l = 0.f;
#pragma unroll
    for (int s = 0; s < NSLICE; ++s) {
        a += ws_acc[(size_t)s * (NN * FOUT) + idx];
        l += ws_l[(size_t)s * NN + i];
    }
    float v = a / l;
    out[idx] = (v > 0.f) ? v : expm1f(v);
}

extern "C" void kernel_launch(void* const* d_in, const int* in_sizes, int n_in,
                              void* d_out, int out_size, void* d_ws, size_t ws_size,
                              hipStream_t stream) {
    const float* h      = (const float*)d_in[0];
    const float* edge   = (const float*)d_in[1];
    const int*   adj    = (const int*)d_in[2];
    const float* weight = (const float*)d_in[3];
    const float* att    = (const float*)d_in[4];
    const float* wedge  = (const float*)d_in[5];
    float* out = (float*)d_out;

    unsigned short* whB = (unsigned short*)d_ws;          // 1 MB bf16 frags
    float* src    = (float*)(whB + (size_t)NN * FOUT);    // 8192
    float* dst    = src + NN;                             // 8192
    float* ws_l   = dst + NN;                             // NSLICE*8192
    float* ws_acc = ws_l + (size_t)NSLICE * NN;           // 8 MB

    gat_prep<<<NN / 16, 256, 0, stream>>>(h, edge, weight, att, wedge, whB, src, dst);
    gat_attn<<<dim3(NN / 16, NSLICE), 256, 0, stream>>>(adj, whB, src, dst, ws_acc, ws_l);
    gat_finish<<<NN * FOUT / 256, 256, 0, stream>>>(ws_acc, ws_l, out);
}